// Round 7
// baseline (519.074 us; speedup 1.0000x reference)
//
#include <hip/hip_runtime.h>

#define NB 4
#define NS 2048
#define ND 1024
#define NH 16
#define HD 64

using bf16x8 = __attribute__((ext_vector_type(8))) short;
using f32x4  = __attribute__((ext_vector_type(4))) float;

// Q pre-scale: 1/sqrt(64) * log2(e), folded into the Q projection so attention
// scores come out in log2 units and softmax uses raw v_exp_f32 (2^x).
#define QSCALE 0.1803368801111804f

// fp32 -> bf16 RNE (values are finite; no NaN path needed)
__device__ __forceinline__ unsigned short f2bf(float f) {
  union { float f; unsigned u; } a; a.f = f;
  unsigned r = a.u + 0x7FFF + ((a.u >> 16) & 1);
  return (unsigned short)(r >> 16);
}

__device__ __forceinline__ float exp2_hw(float x) {
  float r;
  asm("v_exp_f32 %0, %1" : "=v"(r) : "v"(x));
  return r;
}

__device__ __forceinline__ void gload_lds16(const void* g, void* l) {
  __builtin_amdgcn_global_load_lds(
      (const __attribute__((address_space(1))) void*)g,
      (__attribute__((address_space(3))) void*)l, 16, 0, 0);
}

// ---------------- RoPE: x fp32 (B,S,D) -> rx bf16 (B*S, D) ----------------
__global__ __launch_bounds__(256) void rope_kernel(const float* __restrict__ x,
                                                   unsigned short* __restrict__ rx) {
  int idx = blockIdx.x * 256 + threadIdx.x;     // B*S*512 threads exactly
  int j  = idx & 511;
  int bs = idx >> 9;
  int s  = bs & (NS - 1);
  const float* xp = x + (size_t)bs * ND;
  float ang = (float)s * __expf((float)j * -0.017988946039f);
  float sn, cs;
  __sincosf(ang, &sn, &cs);
  float x1 = xp[j], x2 = xp[j + 512];
  unsigned short* rp = rx + (size_t)bs * ND;
  rp[j]       = f2bf(x1 * cs - x2 * sn);
  rp[j + 512] = f2bf(x1 * sn + x2 * cs);
}

// ---------------- weights fp32 -> bf16, packed [Wq|Wk|Wv|Wo] ----------------
__global__ __launch_bounds__(256) void wconv_kernel(const float* __restrict__ w0,
                                                    const float* __restrict__ w1,
                                                    const float* __restrict__ w2,
                                                    const float* __restrict__ w3,
                                                    unsigned short* __restrict__ wb) {
  int idx = blockIdx.x * 256 + threadIdx.x;     // 1M threads, 4 elems each
  int e = idx << 2;
  const float* w = (e < (1 << 20)) ? w0 : (e < (2 << 20)) ? w1 : (e < (3 << 20)) ? w2 : w3;
  float4 v = *(const float4*)(w + (e & 0xFFFFF));
  ushort4 o;
  o.x = f2bf(v.x); o.y = f2bf(v.y); o.z = f2bf(v.z); o.w = f2bf(v.w);
  *(ushort4*)(wb + e) = o;
}

// ---------------- QKV projection GEMM (m97-style 128x128, BK=32) ----------------
__global__ __launch_bounds__(256) void gemm_qkv(const unsigned short* __restrict__ A,
                                                const unsigned short* __restrict__ Wb,
                                                const float* __restrict__ bq,
                                                const float* __restrict__ bk,
                                                const float* __restrict__ bv,
                                                unsigned short* __restrict__ q,
                                                unsigned short* __restrict__ k,
                                                unsigned short* __restrict__ vt) {
  __shared__ alignas(16) unsigned short As[128 * 32];
  __shared__ alignas(16) unsigned short Bs[128 * 32];
  const int tid = threadIdx.x;
  const int lane = tid & 63;
  const int wid = tid >> 6;
  const int wm = wid >> 1, wn = wid & 1;
  const int l15 = lane & 15, lg = lane >> 4;
  const int m0 = blockIdx.x * 128;
  const int n0 = blockIdx.y * 128;
  const int z = blockIdx.z;
  const unsigned short* Bp = Wb + ((size_t)z << 20);

  f32x4 acc[4][4] = {};

  for (int k0 = 0; k0 < ND; k0 += 32) {
#pragma unroll
    for (int it = 0; it < 2; ++it) {
      int c = it * 256 + tid;
      int row = c >> 2, kc = (c & 3) << 3;
      int ldsbase = (it * 256 + (tid & 192)) << 3;   // wave-uniform, elements
      gload_lds16(A  + (size_t)(m0 + row) * ND + k0 + kc, As + ldsbase);
      gload_lds16(Bp + (size_t)(n0 + row) * ND + k0 + kc, Bs + ldsbase);
    }
    __syncthreads();
    bf16x8 af[4], bfr[4];
#pragma unroll
    for (int m = 0; m < 4; ++m)
      af[m] = *(const bf16x8*)(As + (wm * 64 + m * 16 + l15) * 32 + lg * 8);
#pragma unroll
    for (int n = 0; n < 4; ++n)
      bfr[n] = *(const bf16x8*)(Bs + (wn * 64 + n * 16 + l15) * 32 + lg * 8);
#pragma unroll
    for (int m = 0; m < 4; ++m)
#pragma unroll
      for (int n = 0; n < 4; ++n)
        acc[m][n] = __builtin_amdgcn_mfma_f32_16x16x32_bf16(af[m], bfr[n], acc[m][n], 0, 0, 0);
    __syncthreads();
  }

  const float* bias = (z == 0) ? bq : (z == 1) ? bk : bv;
#pragma unroll
  for (int n = 0; n < 4; ++n) {
    int col = n0 + wn * 64 + n * 16 + l15;
    float bb = bias[col];
    int hh = col >> 6, dd = col & 63;
#pragma unroll
    for (int m = 0; m < 4; ++m) {
#pragma unroll
      for (int r = 0; r < 4; ++r) {
        int rowi = m0 + wm * 64 + m * 16 + lg * 4 + r;   // C/D: row=(lg)*4+r, col=l15
        int bbi = rowi >> 11, ss = rowi & (NS - 1);
        float vv = acc[m][n][r] + bb;
        if (z == 0) vv *= QSCALE;                        // fold softmax scale+log2e into Q
        unsigned short val = f2bf(vv);
        size_t bhoff = (size_t)(bbi * NH + hh);
        if (z == 0)      q [(bhoff * NS + ss) * HD + dd] = val;
        else if (z == 1) k [(bhoff * NS + ss) * HD + dd] = val;
        else             vt[(bhoff * HD + dd) * NS + ss] = val;
      }
    }
  }
}

// ---------------- flash attention: per block 128 Q rows of one (b,h) ----------------
// KVBLK=32: LDS 24KB -> 4 blocks/CU (grid-limited), double occupancy vs 48KB.
// T2 swizzles on all tiles (chunk ^= row) with pre-swizzled global src (rule #21).
// T13 defer-max THR=4 (exact math; skips rescale group on most tiles).
// T1 bijective XCD swizzle (1024 blocks).
__global__ __launch_bounds__(256) void attn_kernel(const unsigned short* __restrict__ q,
                                                   const unsigned short* __restrict__ k,
                                                   const unsigned short* __restrict__ vt,
                                                   unsigned short* __restrict__ att) {
  __shared__ alignas(16) unsigned short Ks[2][32 * 64];  // [key][hd], chunk^=(row&7)
  __shared__ alignas(16) unsigned short Vs[2][64 * 32];  // [hd][key], chunk^=(row&3)
  __shared__ alignas(16) unsigned short Ps[4][32 * 32];  // per-wave P, chunk^=(row&3)
  const int tid = threadIdx.x;
  const int lane = tid & 63;
  const int w = tid >> 6;
  const int l15 = lane & 15, lg = lane >> 4;

  const int id = blockIdx.x;                  // 1024 blocks
  const int swz = (id & 7) * 128 + (id >> 3); // XCD p -> swz in [p*128, p*128+128)
  const int bh = swz >> 4;
  const int b = bh >> 4, h = bh & 15;
  const int q0 = (swz & 15) * 128;

  const unsigned short* qp = q  + (size_t)bh * NS * HD;
  const unsigned short* kp = k  + (size_t)bh * NS * HD;
  const unsigned short* vp = vt + (size_t)bh * HD * NS;

  bf16x8 qf[2][2];
#pragma unroll
  for (int m = 0; m < 2; ++m)
#pragma unroll
    for (int t = 0; t < 2; ++t)
      qf[m][t] = *(const bf16x8*)(qp + (size_t)(q0 + w * 32 + m * 16 + l15) * HD + t * 32 + lg * 8);

  f32x4 o[2][4] = {};
  float run_m[2][4], run_l[2][4];
#pragma unroll
  for (int m = 0; m < 2; ++m)
#pragma unroll
    for (int r = 0; r < 4; ++r) { run_m[m][r] = -1e30f; run_l[m][r] = 0.f; }

  unsigned short* ps = &Ps[w][0];
  const int ldsbase = (tid & 192) << 3;   // wave-uniform 1KB stripe, in elements

  // stage one 32-key K/V tile; global source pre-swizzled, LDS dest linear
#define STAGE(buf, t0)                                                           \
  {                                                                              \
    int roK = tid >> 3, chK = (tid & 7) ^ (roK & 7);                             \
    gload_lds16(kp + (size_t)((t0) + roK) * HD + (chK << 3), Ks[buf] + ldsbase); \
    int roV = tid >> 2, chV = (tid & 3) ^ (roV & 3);                             \
    gload_lds16(vp + (size_t)roV * NS + (t0) + (chV << 3),   Vs[buf] + ldsbase); \
  }

  STAGE(0, 0);
  __syncthreads();
  int cur = 0;

  for (int t0 = 0; t0 < NS; t0 += 32) {
    if (t0 + 32 < NS) STAGE(cur ^ 1, t0 + 32);

    // S = Q K^T  (rows q at lg*4+r, cols key at n*16+l15), log2 units
    f32x4 sc[2][2] = {};
#pragma unroll
    for (int kk = 0; kk < 2; ++kk)
#pragma unroll
      for (int n = 0; n < 2; ++n) {
        int krow = n * 16 + l15;
        bf16x8 kf = *(const bf16x8*)(Ks[cur] + krow * 64 + (((kk * 4 + lg) ^ (krow & 7)) << 3));
#pragma unroll
        for (int m = 0; m < 2; ++m)
          sc[m][n] = __builtin_amdgcn_mfma_f32_16x16x32_bf16(qf[m][kk], kf, sc[m][n], 0, 0, 0);
      }

    // tile max per q-row
    float mxv[2][4];
    bool need = false;
#pragma unroll
    for (int m = 0; m < 2; ++m)
#pragma unroll
      for (int r = 0; r < 4; ++r) {
        float mx = fmaxf(sc[m][0][r], sc[m][1][r]);
        mx = fmaxf(mx, __shfl_xor(mx, 1));
        mx = fmaxf(mx, __shfl_xor(mx, 2));
        mx = fmaxf(mx, __shfl_xor(mx, 4));
        mx = fmaxf(mx, __shfl_xor(mx, 8));
        mxv[m][r] = mx;
        need = need || (mx > run_m[m][r] + 4.0f);   // T13: 2^4 headroom, exact math
      }
    if (__any(need)) {
#pragma unroll
      for (int m = 0; m < 2; ++m)
#pragma unroll
        for (int r = 0; r < 4; ++r) {
          float nm = fmaxf(run_m[m][r], mxv[m][r]);
          float fac = exp2_hw(run_m[m][r] - nm);
          run_m[m][r] = nm;
          run_l[m][r] *= fac;
#pragma unroll
          for (int n = 0; n < 4; ++n) o[m][n][r] *= fac;
        }
    }

    // P = 2^(S - m), row sums
#pragma unroll
    for (int m = 0; m < 2; ++m)
#pragma unroll
      for (int r = 0; r < 4; ++r) {
        float rs = 0.f;
#pragma unroll
        for (int n = 0; n < 2; ++n) {
          float p = exp2_hw(sc[m][n][r] - run_m[m][r]);
          sc[m][n][r] = p;
          rs += p;
        }
        rs += __shfl_xor(rs, 1);
        rs += __shfl_xor(rs, 2);
        rs += __shfl_xor(rs, 4);
        rs += __shfl_xor(rs, 8);
        run_l[m][r] += rs;
      }

    // P (D-layout) -> per-wave LDS (swizzled) -> A-fragment layout
#pragma unroll
    for (int m = 0; m < 2; ++m)
#pragma unroll
      for (int n = 0; n < 2; ++n)
#pragma unroll
        for (int r = 0; r < 4; ++r) {
          int prow = m * 16 + lg * 4 + r;
          int col = n * 16 + l15;
          ps[prow * 32 + ((((col >> 3) ^ (prow & 3))) << 3) + (col & 7)] = f2bf(sc[m][n][r]);
        }

    bf16x8 pf[2];
#pragma unroll
    for (int m = 0; m < 2; ++m) {
      int prow = m * 16 + l15;
      pf[m] = *(const bf16x8*)(ps + prow * 32 + ((lg ^ (prow & 3)) << 3));
    }

    // O += P V  (B operand from Vs[hd][key], contract over 32 keys = 1 K-step)
#pragma unroll
    for (int n = 0; n < 4; ++n) {
      int vrow = n * 16 + l15;
      bf16x8 vf = *(const bf16x8*)(Vs[cur] + vrow * 32 + ((lg ^ (vrow & 3)) << 3));
#pragma unroll
      for (int m = 0; m < 2; ++m)
        o[m][n] = __builtin_amdgcn_mfma_f32_16x16x32_bf16(pf[m], vf, o[m][n], 0, 0, 0);
    }
    __syncthreads();   // drains prefetch vmcnt + all lgkm; next tile ready
    cur ^= 1;
  }
#undef STAGE

  // normalize + write attended as (b, s, h*64+d) bf16
#pragma unroll
  for (int m = 0; m < 2; ++m)
#pragma unroll
    for (int r = 0; r < 4; ++r) {
      int rowi = q0 + w * 32 + m * 16 + lg * 4 + r;
      float inv = 1.0f / run_l[m][r];
#pragma unroll
      for (int n = 0; n < 4; ++n)
        att[((size_t)(b * NS + rowi)) * ND + h * HD + n * 16 + l15] = f2bf(o[m][n][r] * inv);
    }
}

// ---------------- output projection GEMM -> fp32 ----------------
__global__ __launch_bounds__(256) void gemm_out(const unsigned short* __restrict__ A,
                                                const unsigned short* __restrict__ Bw,
                                                const float* __restrict__ bo,
                                                float* __restrict__ out) {
  __shared__ alignas(16) unsigned short As[128 * 32];
  __shared__ alignas(16) unsigned short Bs[128 * 32];
  const int tid = threadIdx.x;
  const int lane = tid & 63;
  const int wid = tid >> 6;
  const int wm = wid >> 1, wn = wid & 1;
  const int l15 = lane & 15, lg = lane >> 4;
  const int m0 = blockIdx.x * 128;
  const int n0 = blockIdx.y * 128;

  f32x4 acc[4][4] = {};

  for (int k0 = 0; k0 < ND; k0 += 32) {
#pragma unroll
    for (int it = 0; it < 2; ++it) {
      int c = it * 256 + tid;
      int row = c >> 2, kc = (c & 3) << 3;
      int ldsbase = (it * 256 + (tid & 192)) << 3;
      gload_lds16(A  + (size_t)(m0 + row) * ND + k0 + kc, As + ldsbase);
      gload_lds16(Bw + (size_t)(n0 + row) * ND + k0 + kc, Bs + ldsbase);
    }
    __syncthreads();
    bf16x8 af[4], bfr[4];
#pragma unroll
    for (int m = 0; m < 4; ++m)
      af[m] = *(const bf16x8*)(As + (wm * 64 + m * 16 + l15) * 32 + lg * 8);
#pragma unroll
    for (int n = 0; n < 4; ++n)
      bfr[n] = *(const bf16x8*)(Bs + (wn * 64 + n * 16 + l15) * 32 + lg * 8);
#pragma unroll
    for (int m = 0; m < 4; ++m)
#pragma unroll
      for (int n = 0; n < 4; ++n)
        acc[m][n] = __builtin_amdgcn_mfma_f32_16x16x32_bf16(af[m], bfr[n], acc[m][n], 0, 0, 0);
    __syncthreads();
  }

#pragma unroll
  for (int n = 0; n < 4; ++n) {
    int col = n0 + wn * 64 + n * 16 + l15;
    float bb = bo[col];
#pragma unroll
    for (int m = 0; m < 4; ++m)
#pragma unroll
      for (int r = 0; r < 4; ++r) {
        int rowi = m0 + wm * 64 + m * 16 + lg * 4 + r;
        out[(size_t)rowi * ND + col] = acc[m][n][r] + bb;
      }
  }
}

extern "C" void kernel_launch(void* const* d_in, const int* in_sizes, int n_in,
                              void* d_out, int out_size, void* d_ws, size_t ws_size,
                              hipStream_t stream) {
  const float* x  = (const float*)d_in[0];
  const float* Wq = (const float*)d_in[1];
  const float* bq = (const float*)d_in[2];
  const float* Wk = (const float*)d_in[3];
  const float* bk = (const float*)d_in[4];
  const float* Wv = (const float*)d_in[5];
  const float* bv = (const float*)d_in[6];
  const float* Wo = (const float*)d_in[7];
  const float* bo = (const float*)d_in[8];
  float* out = (float*)d_out;

  char* ws = (char*)d_ws;
  const size_t MB = 1024 * 1024;
  unsigned short* rx  = (unsigned short*)(ws);             // 16 MB
  unsigned short* wb  = (unsigned short*)(ws + 16 * MB);   //  8 MB
  unsigned short* qb  = (unsigned short*)(ws + 24 * MB);   // 16 MB
  unsigned short* kb  = (unsigned short*)(ws + 40 * MB);   // 16 MB
  unsigned short* vtb = (unsigned short*)(ws + 56 * MB);   // 16 MB
  unsigned short* att = (unsigned short*)(ws + 72 * MB);   // 16 MB

  rope_kernel<<<dim3(16384), dim3(256), 0, stream>>>(x, rx);
  wconv_kernel<<<dim3(4096), dim3(256), 0, stream>>>(Wq, Wk, Wv, Wo, wb);
  gemm_qkv<<<dim3(64, 8, 3), dim3(256), 0, stream>>>(rx, wb, bq, bk, bv, qb, kb, vtb);
  attn_kernel<<<dim3(1024), dim3(256), 0, stream>>>(qb, kb, vtb, att);
  gemm_out<<<dim3(64, 8), dim3(256), 0, stream>>>(att, wb + 3 * 1048576, bo, out);
}

// Round 8
// 417.415 us; speedup vs baseline: 1.2435x; 1.2435x over previous
//
#include <hip/hip_runtime.h>

#define NB 4
#define NS 2048
#define ND 1024
#define NH 16
#define HD 64

using bf16x8 = __attribute__((ext_vector_type(8))) short;
using f32x4  = __attribute__((ext_vector_type(4))) float;

// Q pre-scale: 1/sqrt(64) * log2(e), folded into the Q projection so attention
// scores come out in log2 units and softmax uses raw v_exp_f32 (2^x).
#define QSCALE 0.1803368801111804f

// fp32 -> bf16 RNE (values are finite; no NaN path needed)
__device__ __forceinline__ unsigned short f2bf(float f) {
  union { float f; unsigned u; } a; a.f = f;
  unsigned r = a.u + 0x7FFF + ((a.u >> 16) & 1);
  return (unsigned short)(r >> 16);
}

__device__ __forceinline__ float exp2_hw(float x) {
  float r;
  asm("v_exp_f32 %0, %1" : "=v"(r) : "v"(x));
  return r;
}

__device__ __forceinline__ void gload_lds16(const void* g, void* l) {
  __builtin_amdgcn_global_load_lds(
      (const __attribute__((address_space(1))) void*)g,
      (__attribute__((address_space(3))) void*)l, 16, 0, 0);
}

// ---------------- RoPE: x fp32 (B,S,D) -> rx bf16 (B*S, D) ----------------
__global__ __launch_bounds__(256) void rope_kernel(const float* __restrict__ x,
                                                   unsigned short* __restrict__ rx) {
  int idx = blockIdx.x * 256 + threadIdx.x;     // B*S*512 threads exactly
  int j  = idx & 511;
  int bs = idx >> 9;
  int s  = bs & (NS - 1);
  const float* xp = x + (size_t)bs * ND;
  float ang = (float)s * __expf((float)j * -0.017988946039f);
  float sn, cs;
  __sincosf(ang, &sn, &cs);
  float x1 = xp[j], x2 = xp[j + 512];
  unsigned short* rp = rx + (size_t)bs * ND;
  rp[j]       = f2bf(x1 * cs - x2 * sn);
  rp[j + 512] = f2bf(x1 * sn + x2 * cs);
}

// ---------------- weights fp32 -> bf16, packed [Wq|Wk|Wv|Wo] ----------------
__global__ __launch_bounds__(256) void wconv_kernel(const float* __restrict__ w0,
                                                    const float* __restrict__ w1,
                                                    const float* __restrict__ w2,
                                                    const float* __restrict__ w3,
                                                    unsigned short* __restrict__ wb) {
  int idx = blockIdx.x * 256 + threadIdx.x;     // 1M threads, 4 elems each
  int e = idx << 2;
  const float* w = (e < (1 << 20)) ? w0 : (e < (2 << 20)) ? w1 : (e < (3 << 20)) ? w2 : w3;
  float4 v = *(const float4*)(w + (e & 0xFFFFF));
  ushort4 o;
  o.x = f2bf(v.x); o.y = f2bf(v.y); o.z = f2bf(v.z); o.w = f2bf(v.w);
  *(ushort4*)(wb + e) = o;
}

// ---------------- QKV projection GEMM (m97-style 128x128, BK=32) ----------------
__global__ __launch_bounds__(256) void gemm_qkv(const unsigned short* __restrict__ A,
                                                const unsigned short* __restrict__ Wb,
                                                const float* __restrict__ bq,
                                                const float* __restrict__ bk,
                                                const float* __restrict__ bv,
                                                unsigned short* __restrict__ q,
                                                unsigned short* __restrict__ k,
                                                unsigned short* __restrict__ vt) {
  __shared__ alignas(16) unsigned short As[128 * 32];
  __shared__ alignas(16) unsigned short Bs[128 * 32];
  const int tid = threadIdx.x;
  const int lane = tid & 63;
  const int wid = tid >> 6;
  const int wm = wid >> 1, wn = wid & 1;
  const int l15 = lane & 15, lg = lane >> 4;
  const int m0 = blockIdx.x * 128;
  const int n0 = blockIdx.y * 128;
  const int z = blockIdx.z;
  const unsigned short* Bp = Wb + ((size_t)z << 20);

  f32x4 acc[4][4] = {};

  for (int k0 = 0; k0 < ND; k0 += 32) {
#pragma unroll
    for (int it = 0; it < 2; ++it) {
      int c = it * 256 + tid;
      int row = c >> 2, kc = (c & 3) << 3;
      int ldsbase = (it * 256 + (tid & 192)) << 3;   // wave-uniform, elements
      gload_lds16(A  + (size_t)(m0 + row) * ND + k0 + kc, As + ldsbase);
      gload_lds16(Bp + (size_t)(n0 + row) * ND + k0 + kc, Bs + ldsbase);
    }
    __syncthreads();
    bf16x8 af[4], bfr[4];
#pragma unroll
    for (int m = 0; m < 4; ++m)
      af[m] = *(const bf16x8*)(As + (wm * 64 + m * 16 + l15) * 32 + lg * 8);
#pragma unroll
    for (int n = 0; n < 4; ++n)
      bfr[n] = *(const bf16x8*)(Bs + (wn * 64 + n * 16 + l15) * 32 + lg * 8);
#pragma unroll
    for (int m = 0; m < 4; ++m)
#pragma unroll
      for (int n = 0; n < 4; ++n)
        acc[m][n] = __builtin_amdgcn_mfma_f32_16x16x32_bf16(af[m], bfr[n], acc[m][n], 0, 0, 0);
    __syncthreads();
  }

  const float* bias = (z == 0) ? bq : (z == 1) ? bk : bv;
#pragma unroll
  for (int n = 0; n < 4; ++n) {
    int col = n0 + wn * 64 + n * 16 + l15;
    float bb = bias[col];
    int hh = col >> 6, dd = col & 63;
#pragma unroll
    for (int m = 0; m < 4; ++m) {
#pragma unroll
      for (int r = 0; r < 4; ++r) {
        int rowi = m0 + wm * 64 + m * 16 + lg * 4 + r;   // C/D: row=(lg)*4+r, col=l15
        int bbi = rowi >> 11, ss = rowi & (NS - 1);
        float vv = acc[m][n][r] + bb;
        if (z == 0) vv *= QSCALE;                        // fold softmax scale+log2e into Q
        unsigned short val = f2bf(vv);
        size_t bhoff = (size_t)(bbi * NH + hh);
        if (z == 0)      q [(bhoff * NS + ss) * HD + dd] = val;
        else if (z == 1) k [(bhoff * NS + ss) * HD + dd] = val;
        else             vt[(bhoff * HD + dd) * NS + ss] = val;
      }
    }
  }
}

// ---------------- flash attention: per block 128 Q rows of one (b,h) ----------------
// R3-validated structure: KVBLK=64 (128B rows -> swizzle covers all 32 banks,
// measured 0 conflicts), double-buffered K/V via global_load_lds w/ pre-swizzled
// source (rule #21), T1 bijective XCD swizzle.
// New vs R3 (VALU-thinning only, exact math): log2-unit scores (QSCALE in Q),
// v_exp_f32 directly, T13 defer-max THR=4.
__global__ __launch_bounds__(256) void attn_kernel(const unsigned short* __restrict__ q,
                                                   const unsigned short* __restrict__ k,
                                                   const unsigned short* __restrict__ vt,
                                                   unsigned short* __restrict__ att) {
  __shared__ alignas(16) unsigned short Ks[2][64 * 64];  // [key][hd], chunk^=(row&7)
  __shared__ alignas(16) unsigned short Vs[2][64 * 64];  // [hd][key], chunk^=(row&7)
  __shared__ alignas(16) unsigned short Ps[4][32 * 64];  // per-wave P, chunk^=(row&7)
  const int tid = threadIdx.x;
  const int lane = tid & 63;
  const int w = tid >> 6;
  const int l15 = lane & 15, lg = lane >> 4;

  const int id = blockIdx.x;                  // 1024 blocks
  const int swz = (id & 7) * 128 + (id >> 3); // XCD p -> swz in [p*128, p*128+128)
  const int bh = swz >> 4;
  const int b = bh >> 4, h = bh & 15;
  const int q0 = (swz & 15) * 128;

  const unsigned short* qp = q  + (size_t)bh * NS * HD;
  const unsigned short* kp = k  + (size_t)bh * NS * HD;
  const unsigned short* vp = vt + (size_t)bh * HD * NS;

  bf16x8 qf[2][2];
#pragma unroll
  for (int m = 0; m < 2; ++m)
#pragma unroll
    for (int t = 0; t < 2; ++t)
      qf[m][t] = *(const bf16x8*)(qp + (size_t)(q0 + w * 32 + m * 16 + l15) * HD + t * 32 + lg * 8);

  f32x4 o[2][4] = {};
  float run_m[2][4], run_l[2][4];
#pragma unroll
  for (int m = 0; m < 2; ++m)
#pragma unroll
    for (int r = 0; r < 4; ++r) { run_m[m][r] = -1e30f; run_l[m][r] = 0.f; }

  unsigned short* ps = &Ps[w][0];

  // stage one K/V tile into buffer `buf` with pre-swizzled global source
  const int c0 = tid;          // chunk ids c0, c0+256 per thread
#define STAGE(buf, t0)                                                          \
  {                                                                             \
    _Pragma("unroll")                                                           \
    for (int it = 0; it < 2; ++it) {                                            \
      int c = it * 256 + c0;                                                    \
      int ro = c >> 3;                                                          \
      int chs = (c & 7) ^ (ro & 7);                                             \
      int ldsbase = (it * 256 + (tid & 192)) << 3;                              \
      gload_lds16(kp + (size_t)((t0) + ro) * HD + (chs << 3), Ks[buf] + ldsbase); \
      gload_lds16(vp + (size_t)ro * NS + (t0) + (chs << 3),   Vs[buf] + ldsbase); \
    }                                                                           \
  }

  STAGE(0, 0);
  __syncthreads();
  int cur = 0;

  for (int t0 = 0; t0 < NS; t0 += 64) {
    if (t0 + 64 < NS) STAGE(cur ^ 1, t0 + 64);

    // S = Q K^T  (A=Q rows, B=K rows; contract over hd=64 in 2 MFMA K-steps), log2 units
    f32x4 sc[2][4] = {};
#pragma unroll
    for (int kk = 0; kk < 2; ++kk)
#pragma unroll
      for (int n = 0; n < 4; ++n) {
        int krow = n * 16 + l15;
        bf16x8 kf = *(const bf16x8*)(Ks[cur] + krow * 64 + (((kk * 4 + lg) ^ (krow & 7)) << 3));
#pragma unroll
        for (int m = 0; m < 2; ++m)
          sc[m][n] = __builtin_amdgcn_mfma_f32_16x16x32_bf16(qf[m][kk], kf, sc[m][n], 0, 0, 0);
      }

    // tile max per q-row
    float mxv[2][4];
    bool need = false;
#pragma unroll
    for (int m = 0; m < 2; ++m)
#pragma unroll
      for (int r = 0; r < 4; ++r) {
        float mx = fmaxf(fmaxf(sc[m][0][r], sc[m][1][r]), fmaxf(sc[m][2][r], sc[m][3][r]));
        mx = fmaxf(mx, __shfl_xor(mx, 1));
        mx = fmaxf(mx, __shfl_xor(mx, 2));
        mx = fmaxf(mx, __shfl_xor(mx, 4));
        mx = fmaxf(mx, __shfl_xor(mx, 8));
        mxv[m][r] = mx;
        need = need || (mx > run_m[m][r] + 4.0f);   // T13: 2^4 headroom, exact math
      }
    if (__any(need)) {
#pragma unroll
      for (int m = 0; m < 2; ++m)
#pragma unroll
        for (int r = 0; r < 4; ++r) {
          float nm = fmaxf(run_m[m][r], mxv[m][r]);
          float fac = exp2_hw(run_m[m][r] - nm);
          run_m[m][r] = nm;
          run_l[m][r] *= fac;
#pragma unroll
          for (int n = 0; n < 4; ++n) o[m][n][r] *= fac;
        }
    }

    // P = 2^(S - m), row sums
#pragma unroll
    for (int m = 0; m < 2; ++m)
#pragma unroll
      for (int r = 0; r < 4; ++r) {
        float rs = 0.f;
#pragma unroll
        for (int n = 0; n < 4; ++n) {
          float p = exp2_hw(sc[m][n][r] - run_m[m][r]);
          sc[m][n][r] = p;
          rs += p;
        }
        rs += __shfl_xor(rs, 1);
        rs += __shfl_xor(rs, 2);
        rs += __shfl_xor(rs, 4);
        rs += __shfl_xor(rs, 8);
        run_l[m][r] += rs;
      }

    // P (D-layout) -> per-wave LDS (swizzled) -> A-fragment layout
#pragma unroll
    for (int m = 0; m < 2; ++m)
#pragma unroll
      for (int n = 0; n < 4; ++n)
#pragma unroll
        for (int r = 0; r < 4; ++r) {
          int prow = m * 16 + lg * 4 + r;
          ps[prow * 64 + ((n * 16 + l15) ^ ((prow & 7) << 3))] = f2bf(sc[m][n][r]);
        }

    bf16x8 pf[2][2];
#pragma unroll
    for (int m = 0; m < 2; ++m)
#pragma unroll
      for (int kk = 0; kk < 2; ++kk)
        pf[m][kk] = *(const bf16x8*)(ps + (m * 16 + l15) * 64 + (((kk * 4 + lg) ^ (l15 & 7)) << 3));

    // O += P V  (B operand from Vs[hd][key], contract over 64 keys)
#pragma unroll
    for (int kk = 0; kk < 2; ++kk)
#pragma unroll
      for (int n = 0; n < 4; ++n) {
        int vrow = n * 16 + l15;
        bf16x8 vf = *(const bf16x8*)(Vs[cur] + vrow * 64 + (((kk * 4 + lg) ^ (vrow & 7)) << 3));
#pragma unroll
        for (int m = 0; m < 2; ++m)
          o[m][n] = __builtin_amdgcn_mfma_f32_16x16x32_bf16(pf[m][kk], vf, o[m][n], 0, 0, 0);
      }
    __syncthreads();   // drains prefetch vmcnt + all lgkm; next tile ready
    cur ^= 1;
  }
#undef STAGE

  // normalize + write attended as (b, s, h*64+d) bf16
#pragma unroll
  for (int m = 0; m < 2; ++m)
#pragma unroll
    for (int r = 0; r < 4; ++r) {
      int rowi = q0 + w * 32 + m * 16 + lg * 4 + r;
      float inv = 1.0f / run_l[m][r];
#pragma unroll
      for (int n = 0; n < 4; ++n)
        att[((size_t)(b * NS + rowi)) * ND + h * HD + n * 16 + l15] = f2bf(o[m][n][r] * inv);
    }
}

// ---------------- output projection GEMM -> fp32 ----------------
__global__ __launch_bounds__(256) void gemm_out(const unsigned short* __restrict__ A,
                                                const unsigned short* __restrict__ Bw,
                                                const float* __restrict__ bo,
                                                float* __restrict__ out) {
  __shared__ alignas(16) unsigned short As[128 * 32];
  __shared__ alignas(16) unsigned short Bs[128 * 32];
  const int tid = threadIdx.x;
  const int lane = tid & 63;
  const int wid = tid >> 6;
  const int wm = wid >> 1, wn = wid & 1;
  const int l15 = lane & 15, lg = lane >> 4;
  const int m0 = blockIdx.x * 128;
  const int n0 = blockIdx.y * 128;

  f32x4 acc[4][4] = {};

  for (int k0 = 0; k0 < ND; k0 += 32) {
#pragma unroll
    for (int it = 0; it < 2; ++it) {
      int c = it * 256 + tid;
      int row = c >> 2, kc = (c & 3) << 3;
      int ldsbase = (it * 256 + (tid & 192)) << 3;
      gload_lds16(A  + (size_t)(m0 + row) * ND + k0 + kc, As + ldsbase);
      gload_lds16(Bw + (size_t)(n0 + row) * ND + k0 + kc, Bs + ldsbase);
    }
    __syncthreads();
    bf16x8 af[4], bfr[4];
#pragma unroll
    for (int m = 0; m < 4; ++m)
      af[m] = *(const bf16x8*)(As + (wm * 64 + m * 16 + l15) * 32 + lg * 8);
#pragma unroll
    for (int n = 0; n < 4; ++n)
      bfr[n] = *(const bf16x8*)(Bs + (wn * 64 + n * 16 + l15) * 32 + lg * 8);
#pragma unroll
    for (int m = 0; m < 4; ++m)
#pragma unroll
      for (int n = 0; n < 4; ++n)
        acc[m][n] = __builtin_amdgcn_mfma_f32_16x16x32_bf16(af[m], bfr[n], acc[m][n], 0, 0, 0);
    __syncthreads();
  }

#pragma unroll
  for (int n = 0; n < 4; ++n) {
    int col = n0 + wn * 64 + n * 16 + l15;
    float bb = bo[col];
#pragma unroll
    for (int m = 0; m < 4; ++m)
#pragma unroll
      for (int r = 0; r < 4; ++r) {
        int rowi = m0 + wm * 64 + m * 16 + lg * 4 + r;
        out[(size_t)rowi * ND + col] = acc[m][n][r] + bb;
      }
  }
}

extern "C" void kernel_launch(void* const* d_in, const int* in_sizes, int n_in,
                              void* d_out, int out_size, void* d_ws, size_t ws_size,
                              hipStream_t stream) {
  const float* x  = (const float*)d_in[0];
  const float* Wq = (const float*)d_in[1];
  const float* bq = (const float*)d_in[2];
  const float* Wk = (const float*)d_in[3];
  const float* bk = (const float*)d_in[4];
  const float* Wv = (const float*)d_in[5];
  const float* bv = (const float*)d_in[6];
  const float* Wo = (const float*)d_in[7];
  const float* bo = (const float*)d_in[8];
  float* out = (float*)d_out;

  char* ws = (char*)d_ws;
  const size_t MB = 1024 * 1024;
  unsigned short* rx  = (unsigned short*)(ws);             // 16 MB
  unsigned short* wb  = (unsigned short*)(ws + 16 * MB);   //  8 MB
  unsigned short* qb  = (unsigned short*)(ws + 24 * MB);   // 16 MB
  unsigned short* kb  = (unsigned short*)(ws + 40 * MB);   // 16 MB
  unsigned short* vtb = (unsigned short*)(ws + 56 * MB);   // 16 MB
  unsigned short* att = (unsigned short*)(ws + 72 * MB);   // 16 MB

  rope_kernel<<<dim3(16384), dim3(256), 0, stream>>>(x, rx);
  wconv_kernel<<<dim3(4096), dim3(256), 0, stream>>>(Wq, Wk, Wv, Wo, wb);
  gemm_qkv<<<dim3(64, 8, 3), dim3(256), 0, stream>>>(rx, wb, bq, bk, bv, qb, kb, vtb);
  attn_kernel<<<dim3(1024), dim3(256), 0, stream>>>(qb, kb, vtb, att);
  gemm_out<<<dim3(64, 8), dim3(256), 0, stream>>>(att, wb + 3 * 1048576, bo, out);
}